// Round 1
// baseline (173.782 us; speedup 1.0000x reference)
//
#include <hip/hip_runtime.h>

// out = 2 * heatmap_loss, since offset_loss / stop_grad(offset_loss/heatmap_loss)
// == heatmap_loss numerically. heatmap_loss = sum_all(w * huber(pred,gt)) / 16.
// So out = sum_all(w * huber) / 8.

__device__ __forceinline__ float hterm(float p, float g) {
    float err  = fabsf(p - g);
    float quad = fminf(err, 1.0f);      // clip(err, 0, delta=1)
    float lin  = err - quad;
    float h    = 0.5f * quad * quad + lin;
    float w    = (g != 0.0f) ? 1.5f : 0.6f;
    return w * h;
}

__global__ void zero_ws_kernel(float* ws) {
    ws[0] = 0.0f;
}

__global__ __launch_bounds__(256) void heatmap_reduce_kernel(
        const float4* __restrict__ pred,
        const float4* __restrict__ gt,
        float* __restrict__ ws, int n4) {
    int tid    = blockIdx.x * blockDim.x + threadIdx.x;
    int stride = gridDim.x * blockDim.x;

    float acc = 0.0f;
    for (int i = tid; i < n4; i += stride) {
        float4 p = pred[i];
        float4 g = gt[i];
        acc += hterm(p.x, g.x);
        acc += hterm(p.y, g.y);
        acc += hterm(p.z, g.z);
        acc += hterm(p.w, g.w);
    }

    // wave-64 reduction
    #pragma unroll
    for (int off = 32; off > 0; off >>= 1)
        acc += __shfl_down(acc, off, 64);

    __shared__ float wsum[4];
    int lane = threadIdx.x & 63;
    int wave = threadIdx.x >> 6;
    if (lane == 0) wsum[wave] = acc;
    __syncthreads();

    if (threadIdx.x == 0) {
        float s = wsum[0] + wsum[1] + wsum[2] + wsum[3];
        atomicAdd(ws, s);
    }
}

__global__ void finalize_kernel(const float* __restrict__ ws, float* __restrict__ out) {
    out[0] = ws[0] * 0.125f;   // 2 * (sum / 16)
}

extern "C" void kernel_launch(void* const* d_in, const int* in_sizes, int n_in,
                              void* d_out, int out_size, void* d_ws, size_t ws_size,
                              hipStream_t stream) {
    const float* pred = (const float*)d_in[0];
    const float* gt   = (const float*)d_in[1];
    float* out = (float*)d_out;
    float* acc = (float*)d_ws;

    int n  = in_sizes[0];        // 2*8*64*128*128 = 16,777,216 (divisible by 4)
    int n4 = n >> 2;

    zero_ws_kernel<<<1, 1, 0, stream>>>(acc);

    const int block = 256;
    const int grid  = 4096;      // 16 wg/CU; each thread does 4 float4 iters
    heatmap_reduce_kernel<<<grid, block, 0, stream>>>(
        (const float4*)pred, (const float4*)gt, acc, n4);

    finalize_kernel<<<1, 1, 0, stream>>>(acc, out);
}

// Round 2
// 151.500 us; speedup vs baseline: 1.1471x; 1.1471x over previous
//
#include <hip/hip_runtime.h>

// out = 2 * heatmap_loss (offset term cancels: o / stopgrad(o/h) == h).
// heatmap_loss = sum_all(w * huber(pred,gt)) / 16  ->  out = sum/8.

__device__ __forceinline__ float hterm(float p, float g) {
    float err  = fabsf(p - g);
    float quad = fminf(err, 1.0f);      // clip(err, 0, delta=1)
    float lin  = err - quad;
    float h    = 0.5f * quad * quad + lin;
    float w    = (g != 0.0f) ? 1.5f : 0.6f;
    return w * h;
}

__device__ __forceinline__ float hterm4(float4 p, float4 g) {
    return hterm(p.x, g.x) + hterm(p.y, g.y) + hterm(p.z, g.z) + hterm(p.w, g.w);
}

// Each thread: 4 independent float4 loads from each input (8 loads, 128 B/lane
// in flight) -> high memory-level parallelism, no loop-carried waitcnt.
__global__ __launch_bounds__(256) void heatmap_reduce_kernel(
        const float4* __restrict__ pred,
        const float4* __restrict__ gt,
        float* __restrict__ partial) {
    const int tid    = blockIdx.x * 256 + threadIdx.x;
    const int stride = gridDim.x * 256;

    // issue all loads before any use
    float4 p0 = pred[tid];
    float4 p1 = pred[tid +     stride];
    float4 p2 = pred[tid + 2 * stride];
    float4 p3 = pred[tid + 3 * stride];
    float4 g0 = gt[tid];
    float4 g1 = gt[tid +     stride];
    float4 g2 = gt[tid + 2 * stride];
    float4 g3 = gt[tid + 3 * stride];

    float acc = hterm4(p0, g0) + hterm4(p1, g1) + hterm4(p2, g2) + hterm4(p3, g3);

    #pragma unroll
    for (int off = 32; off > 0; off >>= 1)
        acc += __shfl_down(acc, off, 64);

    __shared__ float wsum[4];
    int lane = threadIdx.x & 63;
    int wave = threadIdx.x >> 6;
    if (lane == 0) wsum[wave] = acc;
    __syncthreads();

    if (threadIdx.x == 0)
        partial[blockIdx.x] = wsum[0] + wsum[1] + wsum[2] + wsum[3];
}

__global__ __launch_bounds__(256) void finalize_kernel(
        const float* __restrict__ partial, float* __restrict__ out, int nblocks) {
    float s = 0.0f;
    for (int i = threadIdx.x; i < nblocks; i += 256)
        s += partial[i];

    #pragma unroll
    for (int off = 32; off > 0; off >>= 1)
        s += __shfl_down(s, off, 64);

    __shared__ float wsum[4];
    int lane = threadIdx.x & 63;
    int wave = threadIdx.x >> 6;
    if (lane == 0) wsum[wave] = s;
    __syncthreads();

    if (threadIdx.x == 0)
        out[0] = (wsum[0] + wsum[1] + wsum[2] + wsum[3]) * 0.125f;
}

extern "C" void kernel_launch(void* const* d_in, const int* in_sizes, int n_in,
                              void* d_out, int out_size, void* d_ws, size_t ws_size,
                              hipStream_t stream) {
    const float* pred = (const float*)d_in[0];
    const float* gt   = (const float*)d_in[1];
    float* out     = (float*)d_out;
    float* partial = (float*)d_ws;

    int n  = in_sizes[0];        // 2*8*64*128*128 = 16,777,216
    int n4 = n >> 2;             // 4,194,304 float4s

    const int block = 256;
    const int grid  = n4 / (block * 4);   // 4096: each thread exactly 4 float4s/input

    heatmap_reduce_kernel<<<grid, block, 0, stream>>>(
        (const float4*)pred, (const float4*)gt, partial);

    finalize_kernel<<<1, block, 0, stream>>>(partial, out, grid);
}

// Round 3
// 142.135 us; speedup vs baseline: 1.2227x; 1.0659x over previous
//
#include <hip/hip_runtime.h>

// out = 2 * heatmap_loss (offset term cancels: o / stopgrad(o/h) == h).
// heatmap_loss = sum_all(w * huber(pred,gt)) / 16  ->  out = sum/8.

__device__ __forceinline__ float hterm(float p, float g) {
    float err  = fabsf(p - g);
    float quad = fminf(err, 1.0f);      // clip(err, 0, delta=1)
    float lin  = err - quad;
    float h    = 0.5f * quad * quad + lin;
    float w    = (g != 0.0f) ? 1.5f : 0.6f;
    return w * h;
}

__device__ __forceinline__ float hterm4(float4 p, float4 g) {
    return hterm(p.x, g.x) + hterm(p.y, g.y) + hterm(p.z, g.z) + hterm(p.w, g.w);
}

// Persistent blocks, double-buffered unrolled loop: 4 batches of 4 float4-pairs
// per thread; batch b+1's 8 loads issue before batch b is consumed, so every
// wave keeps 8-16 loads in flight for its whole lifetime.
#define BATCH 4
#define NBATCH 4

__global__ __launch_bounds__(256) void heatmap_reduce_kernel(
        const float4* __restrict__ pred,
        const float4* __restrict__ gt,
        float* __restrict__ partial, int stride) {
    const int tid = blockIdx.x * 256 + threadIdx.x;

    float4 p[2][BATCH], g[2][BATCH];

    #pragma unroll
    for (int j = 0; j < BATCH; ++j) {
        p[0][j] = pred[tid + j * stride];
        g[0][j] = gt[tid + j * stride];
    }

    float acc = 0.0f;
    #pragma unroll
    for (int b = 0; b < NBATCH; ++b) {
        const int cur = b & 1, nxt = cur ^ 1;
        if (b < NBATCH - 1) {
            #pragma unroll
            for (int j = 0; j < BATCH; ++j) {
                p[nxt][j] = pred[tid + ((b + 1) * BATCH + j) * stride];
                g[nxt][j] = gt[tid + ((b + 1) * BATCH + j) * stride];
            }
        }
        #pragma unroll
        for (int j = 0; j < BATCH; ++j)
            acc += hterm4(p[cur][j], g[cur][j]);
    }

    #pragma unroll
    for (int off = 32; off > 0; off >>= 1)
        acc += __shfl_down(acc, off, 64);

    __shared__ float wsum[4];
    int lane = threadIdx.x & 63;
    int wave = threadIdx.x >> 6;
    if (lane == 0) wsum[wave] = acc;
    __syncthreads();

    if (threadIdx.x == 0)
        partial[blockIdx.x] = wsum[0] + wsum[1] + wsum[2] + wsum[3];
}

__global__ __launch_bounds__(256) void finalize_kernel(
        const float* __restrict__ partial, float* __restrict__ out, int nblocks) {
    float s = 0.0f;
    for (int i = threadIdx.x; i < nblocks; i += 256)
        s += partial[i];

    #pragma unroll
    for (int off = 32; off > 0; off >>= 1)
        s += __shfl_down(s, off, 64);

    __shared__ float wsum[4];
    int lane = threadIdx.x & 63;
    int wave = threadIdx.x >> 6;
    if (lane == 0) wsum[wave] = s;
    __syncthreads();

    if (threadIdx.x == 0)
        out[0] = (wsum[0] + wsum[1] + wsum[2] + wsum[3]) * 0.125f;
}

extern "C" void kernel_launch(void* const* d_in, const int* in_sizes, int n_in,
                              void* d_out, int out_size, void* d_ws, size_t ws_size,
                              hipStream_t stream) {
    const float* pred = (const float*)d_in[0];
    const float* gt   = (const float*)d_in[1];
    float* out     = (float*)d_out;
    float* partial = (float*)d_ws;

    int n  = in_sizes[0];        // 2*8*64*128*128 = 16,777,216
    int n4 = n >> 2;             // 4,194,304 float4s

    const int block = 256;
    const int grid  = n4 / (block * BATCH * NBATCH);  // 1024: one co-resident round
    const int stride = grid * block;                  // float4 stride between batch elems

    heatmap_reduce_kernel<<<grid, block, 0, stream>>>(
        (const float4*)pred, (const float4*)gt, partial, stride);

    finalize_kernel<<<1, block, 0, stream>>>(partial, out, grid);
}